// Round 10
// baseline (1386.894 us; speedup 1.0000x reference)
//
#include <hip/hip_runtime.h>
#include <hip/hip_bf16.h>

// QLinear: per-row absmax int8 quant -> int8 GEMM (MFMA) -> fused dequant.
// M=8192, K=4096, N=4096 (derived from in_sizes at launch).

using int32x4 = __attribute__((ext_vector_type(4))) int;

#define QMAXF 127.0f

// ---------------------------------------------------------------------------
// Kernel 0: weight repack (int32-marshalled int8 -> packed int8).
// ---------------------------------------------------------------------------
__global__ __launch_bounds__(256) void repack_weights(
    const int* __restrict__ w, signed char* __restrict__ w8, int total)
{
    bool is32 = true;
#pragma unroll
    for (int i = 0; i < 16; ++i) {
        int v = w[i];
        is32 = is32 && (v >= -127 && v <= 127);
    }

    const int t = blockIdx.x * blockDim.x + threadIdx.x;
    const int nth = gridDim.x * blockDim.x;
    const int chunks = total / 16;

    if (is32) {
        for (int c = t; c < chunks; c += nth) {
            const int32x4* src = reinterpret_cast<const int32x4*>(w + (size_t)c * 16);
            int32x4 a0 = src[0], a1 = src[1], a2 = src[2], a3 = src[3];
            int32x4 o;
            o[0] = (a0[0] & 0xff) | ((a0[1] & 0xff) << 8) | ((a0[2] & 0xff) << 16) | ((a0[3] & 0xff) << 24);
            o[1] = (a1[0] & 0xff) | ((a1[1] & 0xff) << 8) | ((a1[2] & 0xff) << 16) | ((a1[3] & 0xff) << 24);
            o[2] = (a2[0] & 0xff) | ((a2[1] & 0xff) << 8) | ((a2[2] & 0xff) << 16) | ((a2[3] & 0xff) << 24);
            o[3] = (a3[0] & 0xff) | ((a3[1] & 0xff) << 8) | ((a3[2] & 0xff) << 16) | ((a3[3] & 0xff) << 24);
            reinterpret_cast<int32x4*>(w8)[c] = o;
        }
    } else {
        const int32x4* src = reinterpret_cast<const int32x4*>(w);
        int32x4* dst = reinterpret_cast<int32x4*>(w8);
        for (int c = t; c < chunks; c += nth) dst[c] = src[c];
    }
}

// ---------------------------------------------------------------------------
// Kernel 1: per-row absmax quantization. One block (256 thr) per row, K=4096.
// ---------------------------------------------------------------------------
__global__ __launch_bounds__(256) void quant_rows(
    const float* __restrict__ x, signed char* __restrict__ q,
    float* __restrict__ scale, int K)
{
    const int row = blockIdx.x;
    const int t = threadIdx.x;
    const float4* xr = reinterpret_cast<const float4*>(x + (size_t)row * K);

    float4 v[4];
    float m = 0.f;
#pragma unroll
    for (int i = 0; i < 4; ++i) {
        v[i] = xr[t + i * 256];
        m = fmaxf(m, fmaxf(fmaxf(fabsf(v[i].x), fabsf(v[i].y)),
                           fmaxf(fabsf(v[i].z), fabsf(v[i].w))));
    }
#pragma unroll
    for (int off = 32; off >= 1; off >>= 1)
        m = fmaxf(m, __shfl_xor(m, off, 64));
    __shared__ float wmax[4];
    const int wave = t >> 6;
    if ((t & 63) == 0) wmax[wave] = m;
    __syncthreads();
    m = fmaxf(fmaxf(wmax[0], wmax[1]), fmaxf(wmax[2], wmax[3]));

    const float s   = m / QMAXF;
    const float inv = (m > 0.f) ? (QMAXF / m) : 0.f;
    if (t == 0) scale[row] = s;

    int* qr = reinterpret_cast<int*>(q + (size_t)row * K);
#pragma unroll
    for (int i = 0; i < 4; ++i) {
        const float* f = reinterpret_cast<const float*>(&v[i]);
        unsigned int packed = 0;
#pragma unroll
        for (int j = 0; j < 4; ++j) {
            int qi = __float2int_rn(f[j] * inv);
            qi = qi > 127 ? 127 : (qi < -127 ? -127 : qi);
            packed |= ((unsigned int)(qi & 0xff)) << (8 * j);
        }
        qr[t + i * 256] = (int)packed;
    }
}

// ---------------------------------------------------------------------------
// Kernel 2: int8 GEMM, 256x256 tile, 8 waves (2Mx4N), K-step = 64 bytes.
// TWO BLOCKS PER CU (m114 mechanism): NBUF=2 x 32 KB = 64 KiB LDS and
// __launch_bounds__(512,4) (VGPR cap 128 -> 4 waves/SIMD = 2 co-resident
// blocks). Plain 2-phase __syncthreads loop (round-3 structure, verbatim):
// the per-block drain stall at each tile boundary is HIDDEN by the other
// block's MFMA cluster instead of eliminated. Rounds 4/5/7/9 proved that at
// 1 block/CU in barrier lockstep, no intra-block schedule overlaps the LDS
// unit with the MFMA pipe (four schedules, identical 170 us); intra-block
// wave-slip needs >= 6 LDS buffers (192 KB > 160 KB) -- structurally out.
//
// Fragment-order LDS (zero bank conflicts): 1 KB frag-tile fi holds the MFMA
// operand for rows [fi*16,fi*16+16) x 64 k-bytes, lane-linear; per-lane
// global address is row fi*16+(l&15), kcol (l>>4)*16, so every ds_read_b128
// at base + lane*16 is fully linear.
//
// Correctness: stage(t+1) writes buf (t+1)&1, compute(t) reads buf t&1 --
// distinct; __syncthreads() at each tile end emits the full vmcnt(0)+
// lgkmcnt(0)+barrier drain (compiler-enforced), so the NBUF=2 ledger is
// trivially race-free (no hand asm, no fence subtleties).
// ---------------------------------------------------------------------------
#define BM 256
#define BN 256
#define BKB 64
#define NBUF 2

__device__ __forceinline__ void async_copy16(const void* g, void* lds) {
    __builtin_amdgcn_global_load_lds(
        (const __attribute__((address_space(1))) void*)g,
        (__attribute__((address_space(3))) void*)lds, 16, 0, 0);
}

__global__ __launch_bounds__(512, 4) void gemm_i8_dequant_db(
    const signed char* __restrict__ A,   // [M,K] qinp
    const signed char* __restrict__ B,   // [N,K] qweight (packed int8)
    const float* __restrict__ a_scale,   // [M]
    const float* __restrict__ wparams,   // [N]
    const float* __restrict__ bias,      // [N]
    float* __restrict__ out,             // [M,N]
    int M, int N, int K)
{
    __shared__ __align__(16) signed char lds[NBUF * 32768];   // 64 KiB

    const int t    = threadIdx.x;
    const int lane = t & 63;
    const int wave = t >> 6;           // 0..7
    const int wr   = wave >> 2;        // 0..1 (M half)
    const int wc   = wave & 3;         // 0..3 (N quarter)

    // T1: XCD-aware bijective swizzle (nwg % 8 == 0)
    const int nwg = gridDim.x;
    const int cpx = nwg >> 3;
    const int swz = (blockIdx.x & 7) * cpx + (blockIdx.x >> 3);
    const int nbx = N / BN;
    const int rowBase = (swz / nbx) * BM;
    const int colBase = (swz % nbx) * BN;

    const int r15 = lane & 15;
    const int ksl = lane >> 4;

    int32x4 acc[8][4] = {};
    const int NT = K / BKB;            // 64

    const signed char* gA0 = A + (size_t)(rowBase + wave * 16 + r15)       * K + ksl * 16;
    const signed char* gA1 = A + (size_t)(rowBase + (8 + wave) * 16 + r15) * K + ksl * 16;
    const signed char* gB0 = B + (size_t)(colBase + wave * 16 + r15)       * K + ksl * 16;
    const signed char* gB1 = B + (size_t)(colBase + (8 + wave) * 16 + r15) * K + ksl * 16;

    auto stage = [&](int tile) {
        signed char* L = lds + (tile & (NBUF - 1)) * 32768;
        const size_t kt = (size_t)tile * BKB;
        async_copy16(gA0 + kt, L + wave * 1024);
        async_copy16(gA1 + kt, L + (8 + wave) * 1024);
        async_copy16(gB0 + kt, L + 16384 + wave * 1024);
        async_copy16(gB1 + kt, L + 16384 + (8 + wave) * 1024);
    };

    auto compute = [&](int tile) {
        const signed char* Ab = lds + (tile & (NBUF - 1)) * 32768 + wr * 8192 + lane * 16;
        const signed char* Bb = lds + (tile & (NBUF - 1)) * 32768 + 16384 + wc * 4096 + lane * 16;
        int32x4 af[8], bf[4];
#pragma unroll
        for (int nn = 0; nn < 4; ++nn)
            bf[nn] = *reinterpret_cast<const int32x4*>(Bb + nn * 1024);
#pragma unroll
        for (int mm = 0; mm < 8; ++mm)
            af[mm] = *reinterpret_cast<const int32x4*>(Ab + mm * 1024);
        __builtin_amdgcn_s_setprio(1);
#pragma unroll
        for (int mm = 0; mm < 8; ++mm)
#pragma unroll
            for (int nn = 0; nn < 4; ++nn)
                acc[mm][nn] = __builtin_amdgcn_mfma_i32_16x16x64_i8(
                    af[mm], bf[nn], acc[mm][nn], 0, 0, 0);
        __builtin_amdgcn_s_setprio(0);
    };

    // ---- 2-phase double-buffer: stage(t+1) flies during compute(t) ----
    stage(0);
    __syncthreads();
    for (int tt = 0; tt < NT - 1; ++tt) {
        stage(tt + 1);
        compute(tt);
        __syncthreads();               // vmcnt(0)+lgkmcnt(0)+barrier
    }
    compute(NT - 1);

    // ---- epilogue: dequant + bias. C/D map: col=lane&15, row=(lane>>4)*4+r
#pragma unroll
    for (int mm = 0; mm < 8; ++mm) {
        const int rb = rowBase + wr * 128 + mm * 16 + ksl * 4;
        float asc[4];
#pragma unroll
        for (int r = 0; r < 4; ++r) asc[r] = a_scale[rb + r];
#pragma unroll
        for (int nn = 0; nn < 4; ++nn) {
            const int col = colBase + wc * 64 + nn * 16 + r15;
            const float wp = wparams[col];
            const float bs = bias[col];
#pragma unroll
            for (int r = 0; r < 4; ++r) {
                out[(size_t)(rb + r) * N + col] =
                    (float)acc[mm][nn][r] * asc[r] * wp + bs;
            }
        }
    }
}

// ---------------------------------------------------------------------------
extern "C" void kernel_launch(void* const* d_in, const int* in_sizes, int n_in,
                              void* d_out, int out_size, void* d_ws, size_t ws_size,
                              hipStream_t stream) {
    const float* inp     = (const float*)d_in[0];
    const int*   qw_raw  = (const int*)d_in[1];
    const float* wparams = (const float*)d_in[2];
    const float* bias    = (const float*)d_in[3];
    float*       out     = (float*)d_out;

    const int N = in_sizes[2];             // 4096
    const int K = in_sizes[1] / N;         // 4096
    const int M = in_sizes[0] / K;         // 8192

    // workspace: qinp [M*K B] | a_scale [M*4 B, 256-pad] | w8 [N*K B]
    signed char* qinp    = (signed char*)d_ws;
    float*       a_scale = (float*)((char*)d_ws + (size_t)M * K);
    size_t off_w8 = (size_t)M * K + (((size_t)M * sizeof(float) + 255) & ~(size_t)255);
    signed char* w8      = (signed char*)((char*)d_ws + off_w8);

    repack_weights<<<2048, 256, 0, stream>>>(qw_raw, w8, N * K);
    quant_rows<<<M, 256, 0, stream>>>(inp, qinp, a_scale, K);

    const int nwg = (M / BM) * (N / BN);   // 32*16 = 512, %8 == 0
    gemm_i8_dequant_db<<<nwg, 512, 0, stream>>>(
        qinp, w8, a_scale, wparams, bias, out, M, N, K);
}

// Round 11
// 465.425 us; speedup vs baseline: 2.9798x; 2.9798x over previous
//
#include <hip/hip_runtime.h>
#include <hip/hip_bf16.h>

// QLinear: per-row absmax int8 quant -> int8 GEMM (MFMA) -> fused dequant.
// M=8192, K=4096, N=4096 (derived from in_sizes at launch).

using int32x4 = __attribute__((ext_vector_type(4))) int;

#define QMAXF 127.0f

// ---------------------------------------------------------------------------
// Kernel 0: weight repack (int32-marshalled int8 -> packed int8).
// ---------------------------------------------------------------------------
__global__ __launch_bounds__(256) void repack_weights(
    const int* __restrict__ w, signed char* __restrict__ w8, int total)
{
    bool is32 = true;
#pragma unroll
    for (int i = 0; i < 16; ++i) {
        int v = w[i];
        is32 = is32 && (v >= -127 && v <= 127);
    }

    const int t = blockIdx.x * blockDim.x + threadIdx.x;
    const int nth = gridDim.x * blockDim.x;
    const int chunks = total / 16;

    if (is32) {
        for (int c = t; c < chunks; c += nth) {
            const int32x4* src = reinterpret_cast<const int32x4*>(w + (size_t)c * 16);
            int32x4 a0 = src[0], a1 = src[1], a2 = src[2], a3 = src[3];
            int32x4 o;
            o[0] = (a0[0] & 0xff) | ((a0[1] & 0xff) << 8) | ((a0[2] & 0xff) << 16) | ((a0[3] & 0xff) << 24);
            o[1] = (a1[0] & 0xff) | ((a1[1] & 0xff) << 8) | ((a1[2] & 0xff) << 16) | ((a1[3] & 0xff) << 24);
            o[2] = (a2[0] & 0xff) | ((a2[1] & 0xff) << 8) | ((a2[2] & 0xff) << 16) | ((a2[3] & 0xff) << 24);
            o[3] = (a3[0] & 0xff) | ((a3[1] & 0xff) << 8) | ((a3[2] & 0xff) << 16) | ((a3[3] & 0xff) << 24);
            reinterpret_cast<int32x4*>(w8)[c] = o;
        }
    } else {
        const int32x4* src = reinterpret_cast<const int32x4*>(w);
        int32x4* dst = reinterpret_cast<int32x4*>(w8);
        for (int c = t; c < chunks; c += nth) dst[c] = src[c];
    }
}

// ---------------------------------------------------------------------------
// Kernel 1: per-row absmax quantization. One block (256 thr) per row, K=4096.
// ---------------------------------------------------------------------------
__global__ __launch_bounds__(256) void quant_rows(
    const float* __restrict__ x, signed char* __restrict__ q,
    float* __restrict__ scale, int K)
{
    const int row = blockIdx.x;
    const int t = threadIdx.x;
    const float4* xr = reinterpret_cast<const float4*>(x + (size_t)row * K);

    float4 v[4];
    float m = 0.f;
#pragma unroll
    for (int i = 0; i < 4; ++i) {
        v[i] = xr[t + i * 256];
        m = fmaxf(m, fmaxf(fmaxf(fabsf(v[i].x), fabsf(v[i].y)),
                           fmaxf(fabsf(v[i].z), fabsf(v[i].w))));
    }
#pragma unroll
    for (int off = 32; off >= 1; off >>= 1)
        m = fmaxf(m, __shfl_xor(m, off, 64));
    __shared__ float wmax[4];
    const int wave = t >> 6;
    if ((t & 63) == 0) wmax[wave] = m;
    __syncthreads();
    m = fmaxf(fmaxf(wmax[0], wmax[1]), fmaxf(wmax[2], wmax[3]));

    const float s   = m / QMAXF;
    const float inv = (m > 0.f) ? (QMAXF / m) : 0.f;
    if (t == 0) scale[row] = s;

    int* qr = reinterpret_cast<int*>(q + (size_t)row * K);
#pragma unroll
    for (int i = 0; i < 4; ++i) {
        const float* f = reinterpret_cast<const float*>(&v[i]);
        unsigned int packed = 0;
#pragma unroll
        for (int j = 0; j < 4; ++j) {
            int qi = __float2int_rn(f[j] * inv);
            qi = qi > 127 ? 127 : (qi < -127 ? -127 : qi);
            packed |= ((unsigned int)(qi & 0xff)) << (8 * j);
        }
        qr[t + i * 256] = (int)packed;
    }
}

// ---------------------------------------------------------------------------
// Kernel 2: int8 GEMM, 256x256 tile, 8 waves (2Mx4N) -- NO LDS, NO BARRIERS.
//
// Rationale (rounds 4-10): at this tile size a wave needs ~250 registers
// (acc 128 + operand sets + addresses) -> hard cap of 2 waves/SIMD, 1 block/
// CU; under any barriered schedule all waves sit in the same segment, so the
// LDS unit and the MFMA pipe strictly serialize (~3190 cyc/tile vs 1306 MFMA
// floor; four different schedules all measured 170 us). LDS here bought only
// intra-block sharing (Ax4/Bx2) since data is streamed once per block.
//
// This kernel loads MFMA fragments DIRECTLY global->register, double-set
// ping-pong: per K-tile, 32 MFMAs on the current set, then 12
// global_load_dwordx4 refills of that set for tile t+2 (issued one full MFMA
// cluster before consumption; the compiler inserts exact counted vmcnt
// before the consuming cluster -- register loads are the leg it schedules
// well). No barriers -> the two waves/SIMD drift into complementary phases;
// MFMA pipe becomes the only shared serial resource (1306 cyc/tile/SIMD
// floor = ~70 us). Duplicate fragment reads (A by 4 waves, B by 2; 96 KB
// accessed / 32 KB unique per tile per CU) are served by per-CU L1 (32 KB,
// holds the streaming tile) and L2.
//
// Per-instruction access pattern: lanes (l&15)=row, (l>>4)*16=col-offset ->
// 16 rows x 64 contiguous bytes = clean 64B segments; consecutive K-tiles
// complete the 128B L2 lines.
// ---------------------------------------------------------------------------
#define BM 256
#define BN 256
#define BKB 64

__global__ __launch_bounds__(512, 2) void gemm_i8_dequant_reg(
    const signed char* __restrict__ A,   // [M,K] qinp
    const signed char* __restrict__ B,   // [N,K] qweight (packed int8)
    const float* __restrict__ a_scale,   // [M]
    const float* __restrict__ wparams,   // [N]
    const float* __restrict__ bias,      // [N]
    float* __restrict__ out,             // [M,N]
    int M, int N, int K)
{
    const int t    = threadIdx.x;
    const int lane = t & 63;
    const int wave = t >> 6;           // 0..7
    const int wr   = wave >> 2;        // 0..1 (M half)
    const int wc   = wave & 3;         // 0..3 (N quarter)

    // T1: XCD-aware bijective swizzle (nwg % 8 == 0)
    const int nwg = gridDim.x;
    const int cpx = nwg >> 3;
    const int swz = (blockIdx.x & 7) * cpx + (blockIdx.x >> 3);
    const int nbx = N / BN;
    const int rowBase = (swz / nbx) * BM;
    const int colBase = (swz % nbx) * BN;

    const int r15 = lane & 15;
    const int ksl = lane >> 4;

    int32x4 acc[8][4] = {};
    const int NT = K / BKB;            // 64 (even)

    // 32-bit per-lane byte offsets (SGPR base + VGPR offset form saves regs)
    unsigned oA[8], oB[4];
#pragma unroll
    for (int mm = 0; mm < 8; ++mm)
        oA[mm] = (unsigned)((rowBase + (wr * 8 + mm) * 16 + r15) * K + ksl * 16);
#pragma unroll
    for (int nn = 0; nn < 4; ++nn)
        oB[nn] = (unsigned)((colBase + (wc * 4 + nn) * 16 + r15) * K + ksl * 16);

#define LDA(SET, KOFF)                                                        \
    _Pragma("unroll")                                                         \
    for (int mm = 0; mm < 8; ++mm)                                            \
        SET##a[mm] = *reinterpret_cast<const int32x4*>(A + oA[mm] + (KOFF));  \
    _Pragma("unroll")                                                         \
    for (int nn = 0; nn < 4; ++nn)                                            \
        SET##b[nn] = *reinterpret_cast<const int32x4*>(B + oB[nn] + (KOFF));

#define MFMA32(SET)                                                           \
    __builtin_amdgcn_s_setprio(1);                                            \
    _Pragma("unroll")                                                         \
    for (int mm = 0; mm < 8; ++mm)                                            \
        _Pragma("unroll")                                                     \
        for (int nn = 0; nn < 4; ++nn)                                        \
            acc[mm][nn] = __builtin_amdgcn_mfma_i32_16x16x64_i8(              \
                SET##a[mm], SET##b[nn], acc[mm][nn], 0, 0, 0);                \
    __builtin_amdgcn_s_setprio(0);

    int32x4 s0a[8], s0b[4], s1a[8], s1b[4];

    // prologue: tiles 0 and 1 in flight
    LDA(s0, 0u);
    LDA(s1, (unsigned)BKB);

    // steady: compute pair (tt, tt+1), refill with (tt+2, tt+3)
    unsigned kOff = 2u * BKB;
    for (int tt = 0; tt < NT - 2; tt += 2) {
        MFMA32(s0);                    // consume tile tt
        LDA(s0, kOff);                 // refill with tile tt+2 (overlaps s1 MFMAs)
        MFMA32(s1);                    // consume tile tt+1
        LDA(s1, kOff + BKB);           // refill with tile tt+3 (overlaps next s0 MFMAs)
        kOff += 2u * BKB;
    }
    // tail: tiles NT-2, NT-1 already loaded
    MFMA32(s0);
    MFMA32(s1);

#undef LDA
#undef MFMA32

    // ---- epilogue: dequant + bias. C/D map: col=lane&15, row=(lane>>4)*4+r
#pragma unroll
    for (int mm = 0; mm < 8; ++mm) {
        const int rb = rowBase + wr * 128 + mm * 16 + ksl * 4;
        float asc[4];
#pragma unroll
        for (int r = 0; r < 4; ++r) asc[r] = a_scale[rb + r];
#pragma unroll
        for (int nn = 0; nn < 4; ++nn) {
            const int col = colBase + wc * 64 + nn * 16 + r15;
            const float wp = wparams[col];
            const float bs = bias[col];
#pragma unroll
            for (int r = 0; r < 4; ++r) {
                out[(size_t)(rb + r) * N + col] =
                    (float)acc[mm][nn][r] * asc[r] * wp + bs;
            }
        }
    }
}

// ---------------------------------------------------------------------------
extern "C" void kernel_launch(void* const* d_in, const int* in_sizes, int n_in,
                              void* d_out, int out_size, void* d_ws, size_t ws_size,
                              hipStream_t stream) {
    const float* inp     = (const float*)d_in[0];
    const int*   qw_raw  = (const int*)d_in[1];
    const float* wparams = (const float*)d_in[2];
    const float* bias    = (const float*)d_in[3];
    float*       out     = (float*)d_out;

    const int N = in_sizes[2];             // 4096
    const int K = in_sizes[1] / N;         // 4096
    const int M = in_sizes[0] / K;         // 8192

    // workspace: qinp [M*K B] | a_scale [M*4 B, 256-pad] | w8 [N*K B]
    signed char* qinp    = (signed char*)d_ws;
    float*       a_scale = (float*)((char*)d_ws + (size_t)M * K);
    size_t off_w8 = (size_t)M * K + (((size_t)M * sizeof(float) + 255) & ~(size_t)255);
    signed char* w8      = (signed char*)((char*)d_ws + off_w8);

    repack_weights<<<2048, 256, 0, stream>>>(qw_raw, w8, N * K);
    quant_rows<<<M, 256, 0, stream>>>(inp, qinp, a_scale, K);

    const int nwg = (M / BM) * (N / BN);   // 32*16 = 512, %8 == 0
    gemm_i8_dequant_reg<<<nwg, 512, 0, stream>>>(
        qinp, w8, a_scale, wparams, bias, out, M, N, K);
}

// Round 12
// 272.758 us; speedup vs baseline: 5.0847x; 1.7064x over previous
//
#include <hip/hip_runtime.h>
#include <hip/hip_bf16.h>

// QLinear: per-row absmax int8 quant -> int8 GEMM (MFMA) -> fused dequant.
// M=8192, K=4096, N=4096 (derived from in_sizes at launch).

using int32x4 = __attribute__((ext_vector_type(4))) int;

#define QMAXF 127.0f

// ---------------------------------------------------------------------------
// Kernel 0: weight repack (int32-marshalled int8 -> packed int8).
// ---------------------------------------------------------------------------
__global__ __launch_bounds__(256) void repack_weights(
    const int* __restrict__ w, signed char* __restrict__ w8, int total)
{
    bool is32 = true;
#pragma unroll
    for (int i = 0; i < 16; ++i) {
        int v = w[i];
        is32 = is32 && (v >= -127 && v <= 127);
    }

    const int t = blockIdx.x * blockDim.x + threadIdx.x;
    const int nth = gridDim.x * blockDim.x;
    const int chunks = total / 16;

    if (is32) {
        for (int c = t; c < chunks; c += nth) {
            const int32x4* src = reinterpret_cast<const int32x4*>(w + (size_t)c * 16);
            int32x4 a0 = src[0], a1 = src[1], a2 = src[2], a3 = src[3];
            int32x4 o;
            o[0] = (a0[0] & 0xff) | ((a0[1] & 0xff) << 8) | ((a0[2] & 0xff) << 16) | ((a0[3] & 0xff) << 24);
            o[1] = (a1[0] & 0xff) | ((a1[1] & 0xff) << 8) | ((a1[2] & 0xff) << 16) | ((a1[3] & 0xff) << 24);
            o[2] = (a2[0] & 0xff) | ((a2[1] & 0xff) << 8) | ((a2[2] & 0xff) << 16) | ((a2[3] & 0xff) << 24);
            o[3] = (a3[0] & 0xff) | ((a3[1] & 0xff) << 8) | ((a3[2] & 0xff) << 16) | ((a3[3] & 0xff) << 24);
            reinterpret_cast<int32x4*>(w8)[c] = o;
        }
    } else {
        const int32x4* src = reinterpret_cast<const int32x4*>(w);
        int32x4* dst = reinterpret_cast<int32x4*>(w8);
        for (int c = t; c < chunks; c += nth) dst[c] = src[c];
    }
}

// ---------------------------------------------------------------------------
// Kernel 1: per-row absmax quantization. One block (256 thr) per row, K=4096.
// ---------------------------------------------------------------------------
__global__ __launch_bounds__(256) void quant_rows(
    const float* __restrict__ x, signed char* __restrict__ q,
    float* __restrict__ scale, int K)
{
    const int row = blockIdx.x;
    const int t = threadIdx.x;
    const float4* xr = reinterpret_cast<const float4*>(x + (size_t)row * K);

    float4 v[4];
    float m = 0.f;
#pragma unroll
    for (int i = 0; i < 4; ++i) {
        v[i] = xr[t + i * 256];
        m = fmaxf(m, fmaxf(fmaxf(fabsf(v[i].x), fabsf(v[i].y)),
                           fmaxf(fabsf(v[i].z), fabsf(v[i].w))));
    }
#pragma unroll
    for (int off = 32; off >= 1; off >>= 1)
        m = fmaxf(m, __shfl_xor(m, off, 64));
    __shared__ float wmax[4];
    const int wave = t >> 6;
    if ((t & 63) == 0) wmax[wave] = m;
    __syncthreads();
    m = fmaxf(fmaxf(wmax[0], wmax[1]), fmaxf(wmax[2], wmax[3]));

    const float s   = m / QMAXF;
    const float inv = (m > 0.f) ? (QMAXF / m) : 0.f;
    if (t == 0) scale[row] = s;

    int* qr = reinterpret_cast<int*>(q + (size_t)row * K);
#pragma unroll
    for (int i = 0; i < 4; ++i) {
        const float* f = reinterpret_cast<const float*>(&v[i]);
        unsigned int packed = 0;
#pragma unroll
        for (int j = 0; j < 4; ++j) {
            int qi = __float2int_rn(f[j] * inv);
            qi = qi > 127 ? 127 : (qi < -127 ? -127 : qi);
            packed |= ((unsigned int)(qi & 0xff)) << (8 * j);
        }
        qr[t + i * 256] = (int)packed;
    }
}

// ---------------------------------------------------------------------------
// Kernel 2: int8 GEMM, 256x256 tile, 8 waves (2Mx4N), K-step = 64 bytes.
// HYBRID operand paths (AITER flatmm pattern):
//   A -> LDS via global_load_lds (16 KB/tile staged, 64 KB/tile ds_read)
//   B -> DIRECT global->register ping-pong (4 global_load_dwordx4 per wave
//        per tile, issued one full tile (~1300 cyc of MFMA) before use;
//        compiler inserts exact counted vmcnt for register loads)
//
// Rationale (rounds 3-11 ledger): with both operands through LDS, the LDS
// unit serves 96 KB reads + 32 KB DMA per tile (~1540 cyc) > MFMA (1306) ->
// LDS-bound; in 1-block lockstep they serialize (3190 cyc, four schedules
// identical at 170 us). 2 co-resident blocks (r8) double LDS contention:
// worse. No LDS at all (r11) overloads L1/latency: 442 us. Moving ONLY B
// off LDS cuts LDS demand to ~940 cyc < MFMA, keeps B in L1 (16 KB/tile/CU
// working set), and keeps the load count per wave at 4 (vs r11's 24).
//
// Fragment-order LDS for A (zero bank conflicts): 1 KB frag-tile fi holds
// rows [fi*16,fi*16+16) x 64 k-bytes, lane-linear; per-lane global address
// row fi*16+(l&15), kcol (l>>4)*16 -> ds_read_b128 at base+lane*16 linear.
//
// Correctness: plain __syncthreads 2-phase (r3 structure): stage A(t+1) into
// buf (t+1)&1 while computing t from buf t&1; __syncthreads drains
// vmcnt(0)+lgkmcnt(0) (B loads issued this iter are also complete -- they
// were issued before the MFMA cluster, ~650+ cyc earlier). B ping-pong uses
// explicit named sets + unroll-by-2 (static indexing, rule #20).
// ---------------------------------------------------------------------------
#define BM 256
#define BN 256
#define BKB 64
#define NBUF 2

__device__ __forceinline__ void async_copy16(const void* g, void* lds) {
    __builtin_amdgcn_global_load_lds(
        (const __attribute__((address_space(1))) void*)g,
        (__attribute__((address_space(3))) void*)lds, 16, 0, 0);
}

__global__ __launch_bounds__(512, 2) void gemm_i8_dequant_hy(
    const signed char* __restrict__ A,   // [M,K] qinp
    const signed char* __restrict__ B,   // [N,K] qweight (packed int8)
    const float* __restrict__ a_scale,   // [M]
    const float* __restrict__ wparams,   // [N]
    const float* __restrict__ bias,      // [N]
    float* __restrict__ out,             // [M,N]
    int M, int N, int K)
{
    __shared__ __align__(16) signed char lds[NBUF * 16384];   // 32 KiB (A only)

    const int t    = threadIdx.x;
    const int lane = t & 63;
    const int wave = t >> 6;           // 0..7
    const int wr   = wave >> 2;        // 0..1 (M half)
    const int wc   = wave & 3;         // 0..3 (N quarter)

    // T1: XCD-aware bijective swizzle (nwg % 8 == 0)
    const int nwg = gridDim.x;
    const int cpx = nwg >> 3;
    const int swz = (blockIdx.x & 7) * cpx + (blockIdx.x >> 3);
    const int nbx = N / BN;
    const int rowBase = (swz / nbx) * BM;
    const int colBase = (swz % nbx) * BN;

    const int r15 = lane & 15;
    const int ksl = lane >> 4;

    int32x4 acc[8][4] = {};
    const int NT = K / BKB;            // 64 (even)

    // A staging addresses (frag fi = wave, 8+wave)
    const signed char* gA0 = A + (size_t)(rowBase + wave * 16 + r15)       * K + ksl * 16;
    const signed char* gA1 = A + (size_t)(rowBase + (8 + wave) * 16 + r15) * K + ksl * 16;
    // B direct-load addresses (4 fragments per wave)
    const signed char* gB[4];
#pragma unroll
    for (int nn = 0; nn < 4; ++nn)
        gB[nn] = B + (size_t)(colBase + (wc * 4 + nn) * 16 + r15) * K + ksl * 16;

    auto stageA = [&](int tile) {
        signed char* L = lds + (tile & (NBUF - 1)) * 16384;
        const size_t kt = (size_t)tile * BKB;
        async_copy16(gA0 + kt, L + wave * 1024);
        async_copy16(gA1 + kt, L + (8 + wave) * 1024);
    };

#define LDB(SET, TILE)                                                        \
    _Pragma("unroll")                                                         \
    for (int nn = 0; nn < 4; ++nn)                                            \
        SET[nn] = *reinterpret_cast<const int32x4*>(                          \
            gB[nn] + (size_t)(TILE) * BKB);

    auto computeA = [&](int tile, const int32x4 (&bf)[4]) {
        const signed char* Ab = lds + (tile & (NBUF - 1)) * 16384
                              + wr * 8192 + lane * 16;
        int32x4 af[8];
#pragma unroll
        for (int mm = 0; mm < 8; ++mm)
            af[mm] = *reinterpret_cast<const int32x4*>(Ab + mm * 1024);
        __builtin_amdgcn_s_setprio(1);
#pragma unroll
        for (int mm = 0; mm < 8; ++mm)
#pragma unroll
            for (int nn = 0; nn < 4; ++nn)
                acc[mm][nn] = __builtin_amdgcn_mfma_i32_16x16x64_i8(
                    af[mm], bf[nn], acc[mm][nn], 0, 0, 0);
        __builtin_amdgcn_s_setprio(0);
    };

    int32x4 b0[4], b1[4];

    // ---- prologue ----
    stageA(0);
    LDB(b0, 0);
    __syncthreads();                   // A(0) DMA + B(0) loads complete

    // ---- steady, unrolled by 2 (static B ping-pong) ----
    for (int tt = 0; tt < NT - 2; tt += 2) {
        stageA(tt + 1);
        LDB(b1, tt + 1);               // in flight across the MFMA cluster
        computeA(tt, b0);
        __syncthreads();

        stageA(tt + 2);
        LDB(b0, tt + 2);
        computeA(tt + 1, b1);
        __syncthreads();
    }
    // ---- tail: tiles NT-2, NT-1 ----
    stageA(NT - 1);
    LDB(b1, NT - 1);
    computeA(NT - 2, b0);
    __syncthreads();
    computeA(NT - 1, b1);

#undef LDB

    // ---- epilogue: dequant + bias. C/D map: col=lane&15, row=(lane>>4)*4+r
#pragma unroll
    for (int mm = 0; mm < 8; ++mm) {
        const int rb = rowBase + wr * 128 + mm * 16 + ksl * 4;
        float asc[4];
#pragma unroll
        for (int r = 0; r < 4; ++r) asc[r] = a_scale[rb + r];
#pragma unroll
        for (int nn = 0; nn < 4; ++nn) {
            const int col = colBase + wc * 64 + nn * 16 + r15;
            const float wp = wparams[col];
            const float bs = bias[col];
#pragma unroll
            for (int r = 0; r < 4; ++r) {
                out[(size_t)(rb + r) * N + col] =
                    (float)acc[mm][nn][r] * asc[r] * wp + bs;
            }
        }
    }
}

// ---------------------------------------------------------------------------
extern "C" void kernel_launch(void* const* d_in, const int* in_sizes, int n_in,
                              void* d_out, int out_size, void* d_ws, size_t ws_size,
                              hipStream_t stream) {
    const float* inp     = (const float*)d_in[0];
    const int*   qw_raw  = (const int*)d_in[1];
    const float* wparams = (const float*)d_in[2];
    const float* bias    = (const float*)d_in[3];
    float*       out     = (float*)d_out;

    const int N = in_sizes[2];             // 4096
    const int K = in_sizes[1] / N;         // 4096
    const int M = in_sizes[0] / K;         // 8192

    // workspace: qinp [M*K B] | a_scale [M*4 B, 256-pad] | w8 [N*K B]
    signed char* qinp    = (signed char*)d_ws;
    float*       a_scale = (float*)((char*)d_ws + (size_t)M * K);
    size_t off_w8 = (size_t)M * K + (((size_t)M * sizeof(float) + 255) & ~(size_t)255);
    signed char* w8      = (signed char*)((char*)d_ws + off_w8);

    repack_weights<<<2048, 256, 0, stream>>>(qw_raw, w8, N * K);
    quant_rows<<<M, 256, 0, stream>>>(inp, qinp, a_scale, K);

    const int nwg = (M / BM) * (N / BN);   // 32*16 = 512, %8 == 0
    gemm_i8_dequant_hy<<<nwg, 512, 0, stream>>>(
        qinp, w8, a_scale, wparams, bias, out, M, N, K);
}

// Round 13
// 216.658 us; speedup vs baseline: 6.4013x; 1.2589x over previous
//
#include <hip/hip_runtime.h>
#include <hip/hip_bf16.h>

// QLinear: per-row absmax int8 quant -> int8 GEMM (MFMA) -> fused dequant.
// M=8192, K=4096, N=4096 (derived from in_sizes at launch).

using int32x4  = __attribute__((ext_vector_type(4)))  int;
using int32x16 = __attribute__((ext_vector_type(16))) int;

#define QMAXF 127.0f

// ---------------------------------------------------------------------------
// Kernel 0: weight repack (int32-marshalled int8 -> packed int8).
// ---------------------------------------------------------------------------
__global__ __launch_bounds__(256) void repack_weights(
    const int* __restrict__ w, signed char* __restrict__ w8, int total)
{
    bool is32 = true;
#pragma unroll
    for (int i = 0; i < 16; ++i) {
        int v = w[i];
        is32 = is32 && (v >= -127 && v <= 127);
    }

    const int t = blockIdx.x * blockDim.x + threadIdx.x;
    const int nth = gridDim.x * blockDim.x;
    const int chunks = total / 16;

    if (is32) {
        for (int c = t; c < chunks; c += nth) {
            const int32x4* src = reinterpret_cast<const int32x4*>(w + (size_t)c * 16);
            int32x4 a0 = src[0], a1 = src[1], a2 = src[2], a3 = src[3];
            int32x4 o;
            o[0] = (a0[0] & 0xff) | ((a0[1] & 0xff) << 8) | ((a0[2] & 0xff) << 16) | ((a0[3] & 0xff) << 24);
            o[1] = (a1[0] & 0xff) | ((a1[1] & 0xff) << 8) | ((a1[2] & 0xff) << 16) | ((a1[3] & 0xff) << 24);
            o[2] = (a2[0] & 0xff) | ((a2[1] & 0xff) << 8) | ((a2[2] & 0xff) << 16) | ((a2[3] & 0xff) << 24);
            o[3] = (a3[0] & 0xff) | ((a3[1] & 0xff) << 8) | ((a3[2] & 0xff) << 16) | ((a3[3] & 0xff) << 24);
            reinterpret_cast<int32x4*>(w8)[c] = o;
        }
    } else {
        const int32x4* src = reinterpret_cast<const int32x4*>(w);
        int32x4* dst = reinterpret_cast<int32x4*>(w8);
        for (int c = t; c < chunks; c += nth) dst[c] = src[c];
    }
}

// ---------------------------------------------------------------------------
// Kernel 1: per-row absmax quantization. One block (256 thr) per row, K=4096.
// ---------------------------------------------------------------------------
__global__ __launch_bounds__(256) void quant_rows(
    const float* __restrict__ x, signed char* __restrict__ q,
    float* __restrict__ scale, int K)
{
    const int row = blockIdx.x;
    const int t = threadIdx.x;
    const float4* xr = reinterpret_cast<const float4*>(x + (size_t)row * K);

    float4 v[4];
    float m = 0.f;
#pragma unroll
    for (int i = 0; i < 4; ++i) {
        v[i] = xr[t + i * 256];
        m = fmaxf(m, fmaxf(fmaxf(fabsf(v[i].x), fabsf(v[i].y)),
                           fmaxf(fabsf(v[i].z), fabsf(v[i].w))));
    }
#pragma unroll
    for (int off = 32; off >= 1; off >>= 1)
        m = fmaxf(m, __shfl_xor(m, off, 64));
    __shared__ float wmax[4];
    const int wave = t >> 6;
    if ((t & 63) == 0) wmax[wave] = m;
    __syncthreads();
    m = fmaxf(fmaxf(wmax[0], wmax[1]), fmaxf(wmax[2], wmax[3]));

    const float s   = m / QMAXF;
    const float inv = (m > 0.f) ? (QMAXF / m) : 0.f;
    if (t == 0) scale[row] = s;

    int* qr = reinterpret_cast<int*>(q + (size_t)row * K);
#pragma unroll
    for (int i = 0; i < 4; ++i) {
        const float* f = reinterpret_cast<const float*>(&v[i]);
        unsigned int packed = 0;
#pragma unroll
        for (int j = 0; j < 4; ++j) {
            int qi = __float2int_rn(f[j] * inv);
            qi = qi > 127 ? 127 : (qi < -127 ? -127 : qi);
            packed |= ((unsigned int)(qi & 0xff)) << (8 * j);
        }
        qr[t + i * 256] = (int)packed;
    }
}

// ---------------------------------------------------------------------------
// Kernel 2: int8 GEMM, 256x256 tile, 8 waves (2Mx4N), K-step = 64 bytes,
// mfma_i32_32x32x32_i8 (HALF the MFMA instruction count of 16x16x64 at the
// same FLOPs; ubench ceiling 4404 vs 3944 TOPS). Skeleton = round-9's
// proven race-free loop (stage-ahead-3, counted vmcnt, fenced barriers,
// register ping-pong of next tile's fragments overlapping current MFMAs).
//
// Rationale: rounds 4/5/7/9 (four schedules) all pinned at 170 us =
// 3190 cyc/tile vs 1306 cyc of pure MFMA pipe time; barriers, vmcnt policy,
// LDS traffic, and reg-prefetch all had zero effect. At 8 waves the LDS
// unit serves the 96 KB/tile in ~384 cyc (not the wall). The invariant is
// per-instruction cost: 256 MFMA + ~100 mem insts/tile at 2 waves/SIMD ->
// ~12.5 cyc effective per MFMA vs 5.1 ubench. 32x32x32 halves the MFMA
// instruction count (128/tile, 9.1 cyc each) and RF transactions.
//
// Fragment geometry (32x32x32): frag-tile = 32 rows x 32 k-bytes = 1 KB,
// lane-linear (lane l's 16 B at frag*1024 + l*16). Per-lane global source:
// row = fragRow + (l&31), kcol = (l>>5)*16. A/B staged identically ->
// any intra-lane k-permutation cancels between A and B. Zero bank conflicts
// (all ds_read_b128 at wave-uniform base + lane*16).
//
// Per wave per K-tile: 12 ds_read_b128 (A 4mx2k, B 2nx2k) + 16 MFMA.
// acc = int32x16 acc[4][2] = 128 VGPRs. C/D map (m74/m101):
// col = lane&31, row = (reg&3) + 8*(reg>>2) + 4*(lane>>5).
//
// Ledger (= round 9, verified deterministic): stage-ahead-3, 4 DMA/wave/
// tile; steady VM4 retires through tile tt+2 (tt+3 in flight); tails VM4/VM0;
// every barrier two-side fenced (sched_barrier + asm memory clobber).
// ---------------------------------------------------------------------------
#define BM 256
#define BN 256
#define BKB 64
#define NBUF 4

__device__ __forceinline__ void async_copy16(const void* g, void* lds) {
    __builtin_amdgcn_global_load_lds(
        (const __attribute__((address_space(1))) void*)g,
        (__attribute__((address_space(3))) void*)lds, 16, 0, 0);
}

#define BARF do {                                         \
    __builtin_amdgcn_sched_barrier(0);                    \
    asm volatile("" ::: "memory");                        \
    __builtin_amdgcn_s_barrier();                         \
    asm volatile("" ::: "memory");                        \
    __builtin_amdgcn_sched_barrier(0);                    \
} while (0)

#define LGKM0 asm volatile("s_waitcnt lgkmcnt(0)" ::: "memory")
#define VM4   asm volatile("s_waitcnt vmcnt(4)" ::: "memory")
#define VM0   asm volatile("s_waitcnt vmcnt(0)" ::: "memory")

__global__ __launch_bounds__(512, 2) void gemm_i8_dequant_32(
    const signed char* __restrict__ A,   // [M,K] qinp
    const signed char* __restrict__ B,   // [N,K] qweight (packed int8)
    const float* __restrict__ a_scale,   // [M]
    const float* __restrict__ wparams,   // [N]
    const float* __restrict__ bias,      // [N]
    float* __restrict__ out,             // [M,N]
    int M, int N, int K)
{
    __shared__ __align__(16) signed char lds[NBUF * 32768];   // 128 KiB

    const int t    = threadIdx.x;
    const int lane = t & 63;
    const int wave = t >> 6;           // 0..7
    const int wr   = wave >> 2;        // 0..1 (M half: 128 rows)
    const int wc   = wave & 3;         // 0..3 (N quarter: 64 cols)

    // T1: XCD-aware bijective swizzle (nwg % 8 == 0)
    const int nwg = gridDim.x;
    const int cpx = nwg >> 3;
    const int swz = (blockIdx.x & 7) * cpx + (blockIdx.x >> 3);
    const int nbx = N / BN;
    const int rowBase = (swz / nbx) * BM;
    const int colBase = (swz % nbx) * BN;

    const int l31 = lane & 31;
    const int hi  = lane >> 5;         // k-half selector

    int32x16 acc[4][2] = {};
    const int NT = K / BKB;            // 64 (even)

    // staging addresses: wave w stages A frag-ids {w, 8+w}, B likewise.
    // frag-id fid = msub*2 + sl (msub 0..7, sl 0..1); LDS offset fid*1024.
    // global: row = base + msub*32 + l31, col = kt + sl*32 + hi*16.
    const int fid0 = wave, fid1 = 8 + wave;
    const signed char* gA0 = A + (size_t)(rowBase + (fid0 >> 1) * 32 + l31) * K
                               + (fid0 & 1) * 32 + hi * 16;
    const signed char* gA1 = A + (size_t)(rowBase + (fid1 >> 1) * 32 + l31) * K
                               + (fid1 & 1) * 32 + hi * 16;
    const signed char* gB0 = B + (size_t)(colBase + (fid0 >> 1) * 32 + l31) * K
                               + (fid0 & 1) * 32 + hi * 16;
    const signed char* gB1 = B + (size_t)(colBase + (fid1 >> 1) * 32 + l31) * K
                               + (fid1 & 1) * 32 + hi * 16;

    auto stage = [&](int tile) {
        signed char* L = lds + (tile & (NBUF - 1)) * 32768;
        const size_t kt = (size_t)tile * BKB;
        async_copy16(gA0 + kt, L + fid0 * 1024);
        async_copy16(gA1 + kt, L + fid1 * 1024);
        async_copy16(gB0 + kt, L + 16384 + fid0 * 1024);
        async_copy16(gB1 + kt, L + 16384 + fid1 * 1024);
    };

    auto ldFrags = [&](int tile, int32x4 (&fa)[4][2], int32x4 (&fb)[2][2]) {
        const signed char* base = lds + (tile & (NBUF - 1)) * 32768;
        const signed char* Ab = base + (wr * 4) * 2048 + lane * 16;
        const signed char* Bb = base + 16384 + (wc * 2) * 2048 + lane * 16;
#pragma unroll
        for (int mm = 0; mm < 4; ++mm)
#pragma unroll
            for (int sl = 0; sl < 2; ++sl)
                fa[mm][sl] = *reinterpret_cast<const int32x4*>(
                    Ab + (mm * 2 + sl) * 1024);
#pragma unroll
        for (int nn = 0; nn < 2; ++nn)
#pragma unroll
            for (int sl = 0; sl < 2; ++sl)
                fb[nn][sl] = *reinterpret_cast<const int32x4*>(
                    Bb + (nn * 2 + sl) * 1024);
    };

    auto mfmaAll = [&](const int32x4 (&fa)[4][2], const int32x4 (&fb)[2][2]) {
        __builtin_amdgcn_s_setprio(1);
#pragma unroll
        for (int sl = 0; sl < 2; ++sl)
#pragma unroll
            for (int mm = 0; mm < 4; ++mm)
#pragma unroll
                for (int nn = 0; nn < 2; ++nn)
                    acc[mm][nn] = __builtin_amdgcn_mfma_i32_32x32x32_i8(
                        fa[mm][sl], fb[nn][sl], acc[mm][nn], 0, 0, 0);
        __builtin_amdgcn_s_setprio(0);
    };

    int32x4 cA[4][2], cB[2][2], nA[4][2], nB[2][2];

    // ---- prologue: stage tiles 0,1,2; tiles 0,1 proven complete ----
    stage(0); stage(1); stage(2);
    VM4;
    BARF;
    ldFrags(0, cA, cB);

    // ---- steady: pairs tt = 0,2,..  (stages 3..NT-2) ----
    for (int tt = 0; tt + 1 < NT - 3; tt += 2) {
        stage(tt + 3);
        ldFrags(tt + 1, nA, nB);       // executes during mfmaAll below
        mfmaAll(cA, cB);
        VM4; LGKM0; BARF;

        stage(tt + 4);
        ldFrags(tt + 2, cA, cB);
        mfmaAll(nA, nB);
        VM4; LGKM0; BARF;
    }

    // ---- tails: tiles NT-4 .. NT-1 ----
    stage(NT - 1);
    ldFrags(NT - 3, nA, nB);
    mfmaAll(cA, cB);                   // tile NT-4
    VM4; LGKM0; BARF;

    ldFrags(NT - 2, cA, cB);
    mfmaAll(nA, nB);                   // tile NT-3
    VM0; LGKM0; BARF;

    ldFrags(NT - 1, nA, nB);
    mfmaAll(cA, cB);                   // tile NT-2
    mfmaAll(nA, nB);                   // tile NT-1 (compiler inserts lgkm wait)

    // ---- epilogue: dequant + bias.
    // C/D map: col = lane&31, row = (reg&3) + 8*(reg>>2) + 4*hi.
#pragma unroll
    for (int mm = 0; mm < 4; ++mm) {
        const int rb = rowBase + wr * 128 + mm * 32;
        float asc[16];
#pragma unroll
        for (int q = 0; q < 4; ++q)
            *reinterpret_cast<float4*>(&asc[q * 4]) =
                *reinterpret_cast<const float4*>(&a_scale[rb + 8 * q + 4 * hi]);
#pragma unroll
        for (int nn = 0; nn < 2; ++nn) {
            const int col = colBase + wc * 64 + nn * 32 + l31;
            const float wp = wparams[col];
            const float bs = bias[col];
#pragma unroll
            for (int reg = 0; reg < 16; ++reg) {
                const int row = rb + (reg & 3) + 8 * (reg >> 2) + 4 * hi;
                out[(size_t)row * N + col] =
                    (float)acc[mm][nn][reg] * asc[reg] * wp + bs;
            }
        }
    }
}

// ---------------------------------------------------------------------------
extern "C" void kernel_launch(void* const* d_in, const int* in_sizes, int n_in,
                              void* d_out, int out_size, void* d_ws, size_t ws_size,
                              hipStream_t stream) {
    const float* inp     = (const float*)d_in[0];
    const int*   qw_raw  = (const int*)d_in[1];
    const float* wparams = (const float*)d_in[2];
    const float* bias    = (const float*)d_in[3];
    float*       out     = (float*)d_out;

    const int N = in_sizes[2];             // 4096
    const int K = in_sizes[1] / N;         // 4096
    const int M = in_sizes[0] / K;         // 8192

    // workspace: qinp [M*K B] | a_scale [M*4 B, 256-pad] | w8 [N*K B]
    signed char* qinp    = (signed char*)d_ws;
    float*       a_scale = (float*)((char*)d_ws + (size_t)M * K);
    size_t off_w8 = (size_t)M * K + (((size_t)M * sizeof(float) + 255) & ~(size_t)255);
    signed char* w8      = (signed char*)((char*)d_ws + off_w8);

    repack_weights<<<2048, 256, 0, stream>>>(qw_raw, w8, N * K);
    quant_rows<<<M, 256, 0, stream>>>(inp, qinp, a_scale, K);

    const int nwg = (M / BM) * (N / BN);   // 32*16 = 512, %8 == 0
    gemm_i8_dequant_32<<<nwg, 512, 0, stream>>>(
        qinp, w8, a_scale, wparams, bias, out, M, N, K);
}

// Round 14
// 204.733 us; speedup vs baseline: 6.7742x; 1.0582x over previous
//
#include <hip/hip_runtime.h>
#include <hip/hip_bf16.h>

// QLinear: per-row absmax int8 quant -> int8 GEMM (MFMA) -> fused dequant.
// M=8192, K=4096, N=4096 (derived from in_sizes at launch).

using int32x4 = __attribute__((ext_vector_type(4))) int;

#define QMAXF 127.0f

// ---------------------------------------------------------------------------
// Kernel 0: weight repack (int32-marshalled int8 -> packed int8).
// ---------------------------------------------------------------------------
__global__ __launch_bounds__(256) void repack_weights(
    const int* __restrict__ w, signed char* __restrict__ w8, int total)
{
    bool is32 = true;
#pragma unroll
    for (int i = 0; i < 16; ++i) {
        int v = w[i];
        is32 = is32 && (v >= -127 && v <= 127);
    }

    const int t = blockIdx.x * blockDim.x + threadIdx.x;
    const int nth = gridDim.x * blockDim.x;
    const int chunks = total / 16;

    if (is32) {
        for (int c = t; c < chunks; c += nth) {
            const int32x4* src = reinterpret_cast<const int32x4*>(w + (size_t)c * 16);
            int32x4 a0 = src[0], a1 = src[1], a2 = src[2], a3 = src[3];
            int32x4 o;
            o[0] = (a0[0] & 0xff) | ((a0[1] & 0xff) << 8) | ((a0[2] & 0xff) << 16) | ((a0[3] & 0xff) << 24);
            o[1] = (a1[0] & 0xff) | ((a1[1] & 0xff) << 8) | ((a1[2] & 0xff) << 16) | ((a1[3] & 0xff) << 24);
            o[2] = (a2[0] & 0xff) | ((a2[1] & 0xff) << 8) | ((a2[2] & 0xff) << 16) | ((a2[3] & 0xff) << 24);
            o[3] = (a3[0] & 0xff) | ((a3[1] & 0xff) << 8) | ((a3[2] & 0xff) << 16) | ((a3[3] & 0xff) << 24);
            reinterpret_cast<int32x4*>(w8)[c] = o;
        }
    } else {
        const int32x4* src = reinterpret_cast<const int32x4*>(w);
        int32x4* dst = reinterpret_cast<int32x4*>(w8);
        for (int c = t; c < chunks; c += nth) dst[c] = src[c];
    }
}

// ---------------------------------------------------------------------------
// Kernel 1: per-row absmax quantization. One block (256 thr) per row, K=4096.
// ---------------------------------------------------------------------------
__global__ __launch_bounds__(256) void quant_rows(
    const float* __restrict__ x, signed char* __restrict__ q,
    float* __restrict__ scale, int K)
{
    const int row = blockIdx.x;
    const int t = threadIdx.x;
    const float4* xr = reinterpret_cast<const float4*>(x + (size_t)row * K);

    float4 v[4];
    float m = 0.f;
#pragma unroll
    for (int i = 0; i < 4; ++i) {
        v[i] = xr[t + i * 256];
        m = fmaxf(m, fmaxf(fmaxf(fabsf(v[i].x), fabsf(v[i].y)),
                           fmaxf(fabsf(v[i].z), fabsf(v[i].w))));
    }
#pragma unroll
    for (int off = 32; off >= 1; off >>= 1)
        m = fmaxf(m, __shfl_xor(m, off, 64));
    __shared__ float wmax[4];
    const int wave = t >> 6;
    if ((t & 63) == 0) wmax[wave] = m;
    __syncthreads();
    m = fmaxf(fmaxf(wmax[0], wmax[1]), fmaxf(wmax[2], wmax[3]));

    const float s   = m / QMAXF;
    const float inv = (m > 0.f) ? (QMAXF / m) : 0.f;
    if (t == 0) scale[row] = s;

    int* qr = reinterpret_cast<int*>(q + (size_t)row * K);
#pragma unroll
    for (int i = 0; i < 4; ++i) {
        const float* f = reinterpret_cast<const float*>(&v[i]);
        unsigned int packed = 0;
#pragma unroll
        for (int j = 0; j < 4; ++j) {
            int qi = __float2int_rn(f[j] * inv);
            qi = qi > 127 ? 127 : (qi < -127 ? -127 : qi);
            packed |= ((unsigned int)(qi & 0xff)) << (8 * j);
        }
        qr[t + i * 256] = (int)packed;
    }
}

// ---------------------------------------------------------------------------
// Kernel 2: int8 GEMM, 256x256 tile, SIXTEEN waves (4Mx4N, 1024 threads),
// each wave owns a 64x64 sub-tile -> acc[4][4] = 64 VGPR -> total ~115 VGPR
// -> 16 waves/CU = 4 waves/SIMD (DOUBLE every previous round).
//
// Rationale: rounds 3-13 varied schedule (x4), barrier density, vmcnt
// policy, reg-prefetch, operand paths, and MFMA shape -- MfmaUtil pinned at
// 31-35% in every LDS-staged variant. The single untested axis common to
// all: 2 waves/SIMD (acc[8][4]=128 VGPR forced it). The i8 MFMA ubench
// ceilings (3944/4404 TOPS) were measured at 8 waves/SIMD; i8 units run 2x
// the K-depth per instruction of bf16 and plausibly need more wave streams
// to fill the pipe. This kernel holds tile geometry constant and doubles
// the wave streams per SIMD.
//
// Fragment-order LDS (zero bank conflicts): 1 KB frag-tile fi holds the MFMA
// operand for rows [fi*16,fi*16+16) x 64 k-bytes, lane-linear; per-lane
// global source row fi*16+(l&15), kcol (l>>4)*16; every ds_read_b128 at
// wave-uniform base + lane*16 is fully linear. Wave w stages A-frag w and
// B-frag w (1+1 global_load_lds per tile).
//
// Ledger (r9 skeleton, 2 loads/wave/tile, stage-ahead-3, NBUF=4):
//  steady iter t: stage(t+3) -> own outstanding = tiles t+1,t+2,t+3 = 6;
//  VM4 retires the 2 oldest = tile t+1 complete; LGKM0 drains my reads of
//  buf t&3 (rewritten by next iter's stage(t+4)); fenced barrier promotes
//  to all-waves. Prologue: stage 0,1,2; VM4 -> tile 0 in. Tails VM2/VM0.
//  Every barrier two-side fenced (sched_barrier + asm memory clobber).
// ---------------------------------------------------------------------------
#define BM 256
#define BN 256
#define BKB 64
#define NBUF 4

__device__ __forceinline__ void async_copy16(const void* g, void* lds) {
    __builtin_amdgcn_global_load_lds(
        (const __attribute__((address_space(1))) void*)g,
        (__attribute__((address_space(3))) void*)lds, 16, 0, 0);
}

#define BARF do {                                         \
    __builtin_amdgcn_sched_barrier(0);                    \
    asm volatile("" ::: "memory");                        \
    __builtin_amdgcn_s_barrier();                         \
    asm volatile("" ::: "memory");                        \
    __builtin_amdgcn_sched_barrier(0);                    \
} while (0)

#define LGKM0 asm volatile("s_waitcnt lgkmcnt(0)" ::: "memory")
#define VM4   asm volatile("s_waitcnt vmcnt(4)" ::: "memory")
#define VM2   asm volatile("s_waitcnt vmcnt(2)" ::: "memory")
#define VM0   asm volatile("s_waitcnt vmcnt(0)" ::: "memory")

__global__ __launch_bounds__(1024) void gemm_i8_dequant_16w(
    const signed char* __restrict__ A,   // [M,K] qinp
    const signed char* __restrict__ B,   // [N,K] qweight (packed int8)
    const float* __restrict__ a_scale,   // [M]
    const float* __restrict__ wparams,   // [N]
    const float* __restrict__ bias,      // [N]
    float* __restrict__ out,             // [M,N]
    int M, int N, int K)
{
    __shared__ __align__(16) signed char lds[NBUF * 32768];   // 128 KiB

    const int t    = threadIdx.x;
    const int lane = t & 63;
    const int wave = t >> 6;           // 0..15
    const int wr   = wave >> 2;        // 0..3 (M quarter: 64 rows)
    const int wc   = wave & 3;         // 0..3 (N quarter: 64 cols)

    // T1: XCD-aware bijective swizzle (nwg % 8 == 0)
    const int nwg = gridDim.x;
    const int cpx = nwg >> 3;
    const int swz = (blockIdx.x & 7) * cpx + (blockIdx.x >> 3);
    const int nbx = N / BN;
    const int rowBase = (swz / nbx) * BM;
    const int colBase = (swz % nbx) * BN;

    const int r15 = lane & 15;
    const int ksl = lane >> 4;

    int32x4 acc[4][4] = {};
    const int NT = K / BKB;            // 64

    // staging: wave w owns A-frag w and B-frag w (frag = rows [w*16,w*16+16))
    const signed char* gA = A + (size_t)(rowBase + wave * 16 + r15) * K + ksl * 16;
    const signed char* gB = B + (size_t)(colBase + wave * 16 + r15) * K + ksl * 16;

    auto stage = [&](int tile) {
        signed char* L = lds + (tile & (NBUF - 1)) * 32768;
        const size_t kt = (size_t)tile * BKB;
        async_copy16(gA + kt, L + wave * 1024);
        async_copy16(gB + kt, L + 16384 + wave * 1024);
    };

    auto computeTile = [&](int tile) {
        const signed char* Ab = lds + (tile & (NBUF - 1)) * 32768
                              + (wr * 4) * 1024 + lane * 16;
        const signed char* Bb = lds + (tile & (NBUF - 1)) * 32768 + 16384
                              + (wc * 4) * 1024 + lane * 16;
        int32x4 af[4], bf[4];
#pragma unroll
        for (int mm = 0; mm < 4; ++mm)
            af[mm] = *reinterpret_cast<const int32x4*>(Ab + mm * 1024);
#pragma unroll
        for (int nn = 0; nn < 4; ++nn)
            bf[nn] = *reinterpret_cast<const int32x4*>(Bb + nn * 1024);
        __builtin_amdgcn_s_setprio(1);
#pragma unroll
        for (int mm = 0; mm < 4; ++mm)
#pragma unroll
            for (int nn = 0; nn < 4; ++nn)
                acc[mm][nn] = __builtin_amdgcn_mfma_i32_16x16x64_i8(
                    af[mm], bf[nn], acc[mm][nn], 0, 0, 0);
        __builtin_amdgcn_s_setprio(0);
    };

    // ---- prologue: stage tiles 0,1,2 (6 loads/wave); tile 0 proven in ----
    stage(0); stage(1); stage(2);
    VM4;                               // outstanding<=4 -> tile 0 landed
    BARF;

    // ---- steady: t = 0 .. NT-4 ----
    for (int tt = 0; tt < NT - 3; ++tt) {
        stage(tt + 3);
        computeTile(tt);
        VM4;                           // tile tt+1 landed (t+2,t+3 in flight)
        LGKM0;                         // WAR: buf tt&3 reads drained
        BARF;
    }
    // ---- tails ----
    computeTile(NT - 3);
    VM2; LGKM0; BARF;                  // tile NT-2 landed
    computeTile(NT - 2);
    VM0; LGKM0; BARF;                  // tile NT-1 landed
    computeTile(NT - 1);

    // ---- epilogue: dequant + bias. C/D map: col=lane&15, row=(lane>>4)*4+r
#pragma unroll
    for (int mm = 0; mm < 4; ++mm) {
        const int rb = rowBase + wr * 64 + mm * 16 + ksl * 4;
        float asc[4];
#pragma unroll
        for (int r = 0; r < 4; ++r) asc[r] = a_scale[rb + r];
#pragma unroll
        for (int nn = 0; nn < 4; ++nn) {
            const int col = colBase + wc * 64 + nn * 16 + r15;
            const float wp = wparams[col];
            const float bs = bias[col];
#pragma unroll
            for (int r = 0; r < 4; ++r) {
                out[(size_t)(rb + r) * N + col] =
                    (float)acc[mm][nn][r] * asc[r] * wp + bs;
            }
        }
    }
}

// ---------------------------------------------------------------------------
extern "C" void kernel_launch(void* const* d_in, const int* in_sizes, int n_in,
                              void* d_out, int out_size, void* d_ws, size_t ws_size,
                              hipStream_t stream) {
    const float* inp     = (const float*)d_in[0];
    const int*   qw_raw  = (const int*)d_in[1];
    const float* wparams = (const float*)d_in[2];
    const float* bias    = (const float*)d_in[3];
    float*       out     = (float*)d_out;

    const int N = in_sizes[2];             // 4096
    const int K = in_sizes[1] / N;         // 4096
    const int M = in_sizes[0] / K;         // 8192

    // workspace: qinp [M*K B] | a_scale [M*4 B, 256-pad] | w8 [N*K B]
    signed char* qinp    = (signed char*)d_ws;
    float*       a_scale = (float*)((char*)d_ws + (size_t)M * K);
    size_t off_w8 = (size_t)M * K + (((size_t)M * sizeof(float) + 255) & ~(size_t)255);
    signed char* w8      = (signed char*)((char*)d_ws + off_w8);

    repack_weights<<<2048, 256, 0, stream>>>(qw_raw, w8, N * K);
    quant_rows<<<M, 256, 0, stream>>>(inp, qinp, a_scale, K);

    const int nwg = (M / BM) * (N / BN);   // 32*16 = 512, %8 == 0
    gemm_i8_dequant_16w<<<nwg, 1024, 0, stream>>>(
        qinp, w8, a_scale, wparams, bias, out, M, N, K);
}